// Round 2
// baseline (15.301 us; speedup 1.0000x reference)
//
#include <hip/hip_runtime.h>

// ANI radial symmetry function:
//   out[b,a,r] = sum_n exp(-eta[r]*(d-rss[r])^2) * cutoff(d) * mask,  d = r_ij[b,a,n]
//   cutoff(d) = 0.5*(cos(pi*d/3)+1) for d < 3 else 0
// Shapes: r_ij/mask [16,2048,96] f32, etas/rss [16] f32, out [16,2048,16] f32.
//
// v1: no LDS. Thread (row = tid>>4, t = tid&15) owns 6 neighbors (3x float2,
// strided so each 16-lane group reads 128B contiguous -> fully coalesced).
// Each thread evaluates all 16 RBFs into acc[16] (Horner poly in log2 domain,
// v_exp_f32 direct), then a 4-stage halving butterfly over the 16-lane group
// leaves lane t holding the r=t sum -> coalesced store. Removes the v0 16x
// LDS read amplification (48 ds_read_b128/thread -> 0).

#define NN 96
#define RR 16

__global__ __launch_bounds__(256) void ani_radial_kernel(
    const float* __restrict__ r_ij,
    const float* __restrict__ mask,
    const float* __restrict__ etas,
    const float* __restrict__ rss,
    float* __restrict__ out)
{
    const int tid  = threadIdx.x;
    const int rowL = tid >> 4;   // 16 rows per block
    const int t    = tid & 15;   // lane within 16-lane group
    const long long row = (long long)blockIdx.x * 16 + rowL;

    // Per-r Horner constants in log2 domain:
    //   -eta*(d-rs)^2 * log2e = k*d^2 + pb*d + pc
    // etas/rss are uniform (s_load); derived constants are wave-uniform VGPRs.
    const float LOG2E = 1.4426950408889634f;
    float k[RR], pb[RR], pc[RR];
    #pragma unroll
    for (int r = 0; r < RR; ++r) {
        const float eta = etas[r];
        const float rs  = rss[r];
        k[r]  = -eta * LOG2E;
        pb[r] = -2.0f * k[r] * rs;
        pc[r] = k[r] * rs * rs;
    }

    const float* __restrict__ pr = r_ij + row * NN;
    const float* __restrict__ pm = mask + row * NN;

    float acc[RR];
    #pragma unroll
    for (int r = 0; r < RR; ++r) acc[r] = 0.0f;

    // Neighbors n = 32*j + 2*t + {0,1}, j=0..2  -> covers 0..95.
    // For fixed j the 16-lane group reads one contiguous 128B segment.
    float dd[6], mm[6];
    #pragma unroll
    for (int j = 0; j < 3; ++j) {
        const int n = 32 * j + 2 * t;
        const float2 d2 = *reinterpret_cast<const float2*>(pr + n);
        const float2 m2 = *reinterpret_cast<const float2*>(pm + n);
        dd[2*j]   = d2.x; dd[2*j+1] = d2.y;
        mm[2*j]   = m2.x; mm[2*j+1] = m2.y;
    }

    #pragma unroll
    for (int u = 0; u < 6; ++u) {
        const float d = dd[u];
        // cutoff: 0.5*(cos(pi*d/3)+1) = 0.5*(cos(2*pi * d/6)+1); v_cos takes
        // revolutions, arg in [0,0.67) -> no range reduction needed.
        const float c = __builtin_amdgcn_cosf(d * 0.16666666666666666f);
        float w = __builtin_fmaf(0.5f, c, 0.5f);
        w = (d < 3.0f) ? w * mm[u] : 0.0f;
        #pragma unroll
        for (int r = 0; r < RR; ++r) {
            const float e = __builtin_fmaf(__builtin_fmaf(k[r], d, pb[r]), d, pc[r]);
            acc[r] = __builtin_fmaf(__builtin_amdgcn_exp2f(e), w, acc[r]);
        }
    }

    // Halving butterfly transpose-reduce over the 16-lane group.
    // After 4 stages lane t holds sum over the group of original acc[t].
#define RSTAGE(S, NV)                                                   \
    {                                                                   \
        const bool hi = (t & (S)) != 0;                                 \
        _Pragma("unroll")                                               \
        for (int i = 0; i < (NV) / 2; ++i) {                            \
            const float send = hi ? acc[i] : acc[i + (NV) / 2];         \
            const float recv = __shfl_xor(send, (S), 16);               \
            const float keep = hi ? acc[i + (NV) / 2] : acc[i];         \
            acc[i] = keep + recv;                                       \
        }                                                               \
    }
    RSTAGE(8, 16)
    RSTAGE(4, 8)
    RSTAGE(2, 4)
    RSTAGE(1, 2)
#undef RSTAGE

    out[row * RR + t] = acc[0];
}

extern "C" void kernel_launch(void* const* d_in, const int* in_sizes, int n_in,
                              void* d_out, int out_size, void* d_ws, size_t ws_size,
                              hipStream_t stream) {
    const float* r_ij = (const float*)d_in[0];
    const float* mask = (const float*)d_in[1];
    const float* etas = (const float*)d_in[2];
    const float* rss  = (const float*)d_in[3];
    float* out = (float*)d_out;

    const int totalRows = in_sizes[0] / NN;  // B*A = 32768
    const int grid = totalRows / 16;         // 2048 blocks of 256 threads

    ani_radial_kernel<<<grid, 256, 0, stream>>>(r_ij, mask, etas, rss, out);
}